// Round 4
// baseline (4992.003 us; speedup 1.0000x reference)
//
#include <hip/hip_runtime.h>
#include <hip/hip_bf16.h>
#include <stdint.h>

#define XS 128
#define YS 128
#define ZS 8
#define NQ (XS*YS*ZS)        // 131072 queries
#define CDIM 128
#define NH 8
#define HD 16
#define DH 192
#define DW 640
#define NPIX (DH*DW)
#define NVPIX 10080          // 7680 + 1920 + 480

__device__ __forceinline__ float b2f(unsigned short u){
    union { unsigned int i; float f; } v; v.i = ((unsigned int)u) << 16; return v.f;
}
__device__ __forceinline__ unsigned short f2b(float f){
    __hip_bfloat16 h = __float2bfloat16(f);
    return *reinterpret_cast<unsigned short*>(&h);
}

// ---------------- inverse of K (3x3) and E (4x4), fp64, one thread ----------------
__global__ void inv_kernel(const float* __restrict__ K,
                           const float* __restrict__ E,
                           double* __restrict__ inv_out){
    if (threadIdx.x != 0 || blockIdx.x != 0) return;
    double k[3][3], e[4][4];
    for (int i=0;i<9;i++)  k[i/3][i%3] = (double)K[i];
    for (int i=0;i<16;i++) e[i/4][i%4] = (double)E[i];
    double det = k[0][0]*(k[1][1]*k[2][2]-k[1][2]*k[2][1])
               - k[0][1]*(k[1][0]*k[2][2]-k[1][2]*k[2][0])
               + k[0][2]*(k[1][0]*k[2][1]-k[1][1]*k[2][0]);
    double id = 1.0/det;
    double inv[3][3];
    inv[0][0]=(k[1][1]*k[2][2]-k[1][2]*k[2][1])*id;
    inv[0][1]=(k[0][2]*k[2][1]-k[0][1]*k[2][2])*id;
    inv[0][2]=(k[0][1]*k[1][2]-k[0][2]*k[1][1])*id;
    inv[1][0]=(k[1][2]*k[2][0]-k[1][0]*k[2][2])*id;
    inv[1][1]=(k[0][0]*k[2][2]-k[0][2]*k[2][0])*id;
    inv[1][2]=(k[0][2]*k[1][0]-k[0][0]*k[1][2])*id;
    inv[2][0]=(k[1][0]*k[2][1]-k[1][1]*k[2][0])*id;
    inv[2][1]=(k[0][1]*k[2][0]-k[0][0]*k[2][1])*id;
    inv[2][2]=(k[0][0]*k[1][1]-k[0][1]*k[1][0])*id;
    for (int i=0;i<9;i++) inv_out[i] = inv[i/3][i%3];
    double a[4][8];
    for (int i=0;i<4;i++){ for(int j=0;j<4;j++){ a[i][j]=e[i][j]; a[i][4+j]=(i==j)?1.0:0.0; } }
    for (int c=0;c<4;c++){
        int piv=c; double best=fabs(a[c][c]);
        for (int r=c+1;r<4;r++){ double v=fabs(a[r][c]); if (v>best){best=v;piv=r;} }
        if (piv!=c){ for (int j=0;j<8;j++){ double tmp=a[c][j]; a[c][j]=a[piv][j]; a[piv][j]=tmp; } }
        double pv = 1.0/a[c][c];
        for (int j=0;j<8;j++) a[c][j]*=pv;
        for (int r=0;r<4;r++){
            if (r==c) continue;
            double f=a[r][c];
            for(int j=0;j<8;j++) a[r][j]-=f*a[c][j];
        }
    }
    for (int i=0;i<16;i++) inv_out[9+i] = a[i/4][4 + (i%4)];
}

// ---------------- pix2vox + voxel mask ----------------
__global__ void mask_kernel(const float* __restrict__ depth,
                            const double* __restrict__ invm,
                            const float* __restrict__ vorigin,
                            unsigned char* __restrict__ mask){
    int tid = blockIdx.x*blockDim.x + threadIdx.x;
    if (tid >= NPIX) return;
    int gx = tid % DW, gy = tid / DW;
    double d  = (double)depth[tid];
    double X0 = (double)gx * d, X1 = (double)gy * d, X2 = d;
    double c0 = invm[0]*X0 + invm[1]*X1 + invm[2]*X2;
    double c1 = invm[3]*X0 + invm[4]*X1 + invm[5]*X2;
    double c2 = invm[6]*X0 + invm[7]*X1 + invm[8]*X2;
    const double* iE = invm + 9;
    double w0 = iE[0]*c0 + iE[1]*c1 + iE[2]*c2  + iE[3];
    double w1 = iE[4]*c0 + iE[5]*c1 + iE[6]*c2  + iE[7];
    double w2 = iE[8]*c0 + iE[9]*c1 + iE[10]*c2 + iE[11];
    double v0 = (w0-(double)vorigin[0])/0.4 - 0.5;
    double v1 = (w1-(double)vorigin[1])/0.4 - 0.5;
    double v2 = ((w2-(double)vorigin[2])/0.4 - 0.5) / 2.0;
    int xi = (int)v0, yi = (int)v1, zi = (int)v2;
    if (xi>=0 && xi<XS && yi>=0 && yi<YS && zi>=0 && zi<ZS)
        mask[(xi*YS + yi)*ZS + zi] = 1;
}

// ---------------- value = flat @ Wv.T + bv -> bf16, 4 pixels/block ----------------
__global__ __launch_bounds__(128)
void value_kernel(const float* __restrict__ f0,
                  const float* __restrict__ f1,
                  const float* __restrict__ f2,
                  const float* __restrict__ Wv,
                  const float* __restrict__ bv,
                  unsigned short* __restrict__ value){
    int p0 = blockIdx.x*4, t = threadIdx.x;
    __shared__ float fl[CDIM][4];
    const float* src; int hw, lp;
    if (p0 < 7680)      { src=f0; hw=7680; lp=p0; }
    else if (p0 < 9600) { src=f1; hw=1920; lp=p0-7680; }
    else                { src=f2; hw=480;  lp=p0-9600; }
    float4 v = *(const float4*)(src + t*hw + lp);
    fl[t][0]=v.x; fl[t][1]=v.y; fl[t][2]=v.z; fl[t][3]=v.w;
    __syncthreads();
    float bb = bv[t];
    float acc[4] = {bb,bb,bb,bb};
    const float4* wrow = (const float4*)(Wv + t*CDIM);
    #pragma unroll 8
    for (int kc=0; kc<32; ++kc){
        float4 w = wrow[kc];
        #pragma unroll
        for (int u=0;u<4;u++){
            float wu = (u==0)?w.x:(u==1)?w.y:(u==2)?w.z:w.w;
            float4 fv = *(const float4*)fl[kc*4+u];
            acc[0] += fv.x*wu; acc[1] += fv.y*wu; acc[2] += fv.z*wu; acc[3] += fv.w*wu;
        }
    }
    #pragma unroll
    for (int i=0;i<4;i++)
        value[(size_t)(p0+i)*CDIM + t] = f2b(acc[i]);
}

// ---------------- offsets+logits GEMM: [288 x len] bf16, transposed output ----------------
// Block: 256 threads = 4 waves, 64 queries (lane = query). Wave w computes rows
// w*72 .. w*72+71 in 12-row register groups. Weight loads are wave-uniform.
__global__ __launch_bounds__(256)
void offaw_kernel(const float* __restrict__ q_in,      // chunk base
                  const float* __restrict__ Woff,
                  const float* __restrict__ boff,
                  const float* __restrict__ Wattw,
                  const float* __restrict__ battw,
                  unsigned short* __restrict__ offawT, // [288][len]
                  int len){
    const int n0 = blockIdx.x * 64;
    const int t = threadIdx.x;
    __shared__ float Qs[64][129];   // pad 129: conflict-free b32 column reads
    for (int idx = t; idx < 64*CDIM; idx += 256){
        int n = idx >> 7, c = idx & 127;
        Qs[n][c] = q_in[(size_t)(n0+n)*CDIM + c];
    }
    __syncthreads();
    const int w = t >> 6, lane = t & 63;
    for (int g = 0; g < 6; ++g){
        const int j0 = w*72 + g*12;
        const float* Wb; const float* bb;
        if (j0 < 192){ Wb = Woff  + (size_t)j0*CDIM;       bb = boff  + j0; }
        else         { Wb = Wattw + (size_t)(j0-192)*CDIM; bb = battw + (j0-192); }
        float acc[12];
        #pragma unroll
        for (int r=0;r<12;r++) acc[r] = bb[r];
        #pragma unroll 2
        for (int kc = 0; kc < 32; ++kc){
            float q0 = Qs[lane][kc*4+0];
            float q1 = Qs[lane][kc*4+1];
            float q2 = Qs[lane][kc*4+2];
            float q3 = Qs[lane][kc*4+3];
            #pragma unroll
            for (int r=0;r<12;r++){
                float4 w4 = *(const float4*)(Wb + r*CDIM + kc*4);
                acc[r] += q0*w4.x + q1*w4.y + q2*w4.z + q3*w4.w;
            }
        }
        #pragma unroll
        for (int r=0;r<12;r++)
            offawT[(size_t)(j0+r)*len + n0 + lane] = f2b(acc[r]);
    }
}

// ---------------- sampling + Wout + LN + mask + transposed store ----------------
// Block: 256 threads, 16 queries. Sampling map: c=t&15, h=(t>>4)&7, qg=t>>7.
__global__ __launch_bounds__(256)
void attn_kernel(const float* __restrict__ q_in,
                 const float* __restrict__ refpix,
                 const unsigned short* __restrict__ offawT, // [288][len], chunk-local
                 const unsigned short* __restrict__ value,
                 const float* __restrict__ Wout,
                 const float* __restrict__ bout,
                 const float* __restrict__ lng,
                 const float* __restrict__ lnb,
                 const unsigned char* __restrict__ mask,
                 float* __restrict__ dout,
                 int q0g, int len){
    const int n0l = blockIdx.x * 16;        // chunk-local
    const int n0g = q0g + n0l;              // global query index
    const int t = threadIdx.x;
    __shared__ float offaw_s[288][17];
    __shared__ float q_s[16][CDIM];
    __shared__ float out_s[16][CDIM];
    __shared__ float rp_s[32];
    __shared__ float wred[2][4][8];
    __shared__ unsigned char mask_s[16];

    for (int idx = t; idx < 288*16; idx += 256){
        int j = idx >> 4, qi = idx & 15;
        offaw_s[j][qi] = b2f(offawT[(size_t)j*len + n0l + qi]);
    }
    for (int idx = t; idx < 16*CDIM; idx += 256)
        ((float*)q_s)[idx] = q_in[(size_t)n0g*CDIM + idx];
    if (t < 32) rp_s[t] = refpix[n0g*2 + t];
    if (t < 16) mask_s[t] = mask[n0g + t];
    __syncthreads();

    // softmax over 12 per (query, head)
    if (t < 128){
        int qi = t >> 3, h = t & 7;
        float m = -1e30f;
        #pragma unroll
        for (int i=0;i<12;i++) m = fmaxf(m, offaw_s[192+h*12+i][qi]);
        float e[12]; float s = 0.f;
        #pragma unroll
        for (int i=0;i<12;i++){ e[i] = __expf(offaw_s[192+h*12+i][qi]-m); s += e[i]; }
        float is = 1.f/s;
        #pragma unroll
        for (int i=0;i<12;i++) offaw_s[192+h*12+i][qi] = e[i]*is;
    }
    __syncthreads();

    // bilinear sampling, 8 queries per thread
    const int c = t & 15, h = (t>>4)&7, qg = t>>7;
    const unsigned short* vbase = value + h*HD + c;
    float accv[8] = {0.f,0.f,0.f,0.f,0.f,0.f,0.f,0.f};
    const int Wl[3]={160,80,40}, Hl[3]={48,24,12}, stl[3]={0,7680,9600};
    #pragma unroll
    for (int l=0;l<3;l++){
        const float fw = (float)Wl[l], fh = (float)Hl[l];
        float rxf[8], ryf[8];
        #pragma unroll
        for (int qi8=0;qi8<8;qi8++){
            int qi = qg*8+qi8;
            rxf[qi8] = rp_s[qi*2+0]*fw - 0.5f;
            ryf[qi8] = rp_s[qi*2+1]*fh - 0.5f;
        }
        #pragma unroll
        for (int p=0;p<4;p++){
            const int orow = ((h*3+l)*4+p)*2;
            const int arow = 192 + h*12 + l*4 + p;
            #pragma unroll
            for (int qi8=0;qi8<8;qi8++){
                int qi = qg*8+qi8;
                float x = rxf[qi8] + offaw_s[orow][qi];
                float y = ryf[qi8] + offaw_s[orow+1][qi];
                float x0f = floorf(x), y0f = floorf(y);
                float lx = x-x0f, ly = y-y0f;
                int x0 = (int)x0f, y0 = (int)y0f;
                bool x0ok = (x0 >= 0) && (x0 < Wl[l]);
                bool x1ok = (x0+1 >= 0) && (x0+1 < Wl[l]);
                bool y0ok = (y0 >= 0) && (y0 < Hl[l]);
                bool y1ok = (y0+1 >= 0) && (y0+1 < Hl[l]);
                int base = stl[l] + y0*Wl[l] + x0;
                float v00 = (x0ok&&y0ok) ? b2f(vbase[(size_t)base*CDIM])            : 0.f;
                float v01 = (x1ok&&y0ok) ? b2f(vbase[(size_t)(base+1)*CDIM])        : 0.f;
                float v10 = (x0ok&&y1ok) ? b2f(vbase[(size_t)(base+Wl[l])*CDIM])    : 0.f;
                float v11 = (x1ok&&y1ok) ? b2f(vbase[(size_t)(base+Wl[l]+1)*CDIM])  : 0.f;
                float s = (v00*(1.f-lx)+v01*lx)*(1.f-ly) + (v10*(1.f-lx)+v11*lx)*ly;
                accv[qi8] = fmaf(offaw_s[arow][qi], s, accv[qi8]);
            }
        }
    }
    #pragma unroll
    for (int qi8=0;qi8<8;qi8++) out_s[qg*8+qi8][h*HD+c] = accv[qi8];
    __syncthreads();

    // attn = out @ Wout.T + bout, 8 queries per thread (r = t&127)
    const int r = t & 127;
    float acc[8];
    { float bb = bout[r];
      #pragma unroll
      for (int qi8=0;qi8<8;qi8++) acc[qi8]=bb; }
    const float4* w4p = (const float4*)(Wout + (size_t)r*CDIM);
    #pragma unroll 8
    for (int kc=0;kc<32;kc++){
        float4 w = w4p[kc];
        #pragma unroll
        for (int qi8=0;qi8<8;qi8++){
            const float* os = out_s[qg*8+qi8];
            acc[qi8] += os[kc*4+0]*w.x + os[kc*4+1]*w.y
                      + os[kc*4+2]*w.z + os[kc*4+3]*w.w;
        }
    }

    // residual + LayerNorm + mask + transposed store
    const int wv = t >> 6;
    float hv[8], sred[8];
    #pragma unroll
    for (int qi8=0;qi8<8;qi8++){ hv[qi8] = q_s[qg*8+qi8][r] + acc[qi8]; sred[qi8]=hv[qi8]; }
    #pragma unroll
    for (int off=32; off>0; off>>=1)
        #pragma unroll
        for (int qi8=0;qi8<8;qi8++) sred[qi8] += __shfl_xor(sred[qi8], off, 64);
    if ((t&63)==0){
        #pragma unroll
        for (int qi8=0;qi8<8;qi8++) wred[0][wv][qi8]=sred[qi8];
    }
    __syncthreads();
    float mu[8], dv[8];
    #pragma unroll
    for (int qi8=0;qi8<8;qi8++){
        mu[qi8] = (wred[0][qg*2][qi8]+wred[0][qg*2+1][qi8]) * (1.f/128.f);
        dv[qi8] = hv[qi8]-mu[qi8];
        sred[qi8] = dv[qi8]*dv[qi8];
    }
    #pragma unroll
    for (int off=32; off>0; off>>=1)
        #pragma unroll
        for (int qi8=0;qi8<8;qi8++) sred[qi8] += __shfl_xor(sred[qi8], off, 64);
    if ((t&63)==0){
        #pragma unroll
        for (int qi8=0;qi8<8;qi8++) wred[1][wv][qi8]=sred[qi8];
    }
    __syncthreads();

    float res[8];
    const float g = lng[r], b = lnb[r];
    #pragma unroll
    for (int qi8=0;qi8<8;qi8++){
        float var = (wred[1][qg*2][qi8]+wred[1][qg*2+1][qi8]) * (1.f/128.f);
        float nv  = dv[qi8] * __frsqrt_rn(var + 1e-5f) * g + b;
        res[qi8] = mask_s[qg*8+qi8] ? nv : q_s[qg*8+qi8][r];
    }
    float4* dst = (float4*)(dout + (size_t)r*NQ + n0g + qg*8);
    float4 o0; o0.x=res[0]; o0.y=res[1]; o0.z=res[2]; o0.w=res[3];
    float4 o1; o1.x=res[4]; o1.y=res[5]; o1.z=res[6]; o1.w=res[7];
    dst[0] = o0; dst[1] = o1;
}

extern "C" void kernel_launch(void* const* d_in, const int* in_sizes, int n_in,
                              void* d_out, int out_size, void* d_ws, size_t ws_size,
                              hipStream_t stream){
    const float* scene  = (const float*)d_in[0];
    const float* f0     = (const float*)d_in[1];
    const float* f1     = (const float*)d_in[2];
    const float* f2     = (const float*)d_in[3];
    const float* depth  = (const float*)d_in[4];
    const float* K      = (const float*)d_in[5];
    const float* E      = (const float*)d_in[6];
    const float* vorig  = (const float*)d_in[7];
    const float* refpix = (const float*)d_in[8];
    const float* Wv     = (const float*)d_in[9];
    const float* bv     = (const float*)d_in[10];
    const float* Woff   = (const float*)d_in[11];
    const float* boff   = (const float*)d_in[12];
    const float* Wattw  = (const float*)d_in[13];
    const float* battw  = (const float*)d_in[14];
    const float* Wout   = (const float*)d_in[15];
    const float* bout   = (const float*)d_in[16];
    const float* lng    = (const float*)d_in[17];
    const float* lnb    = (const float*)d_in[18];

    char* ws = (char*)d_ws;
    const size_t FIXED = 512 + 131072 + 2580480;           // invm + mask + value
    double*         invm   = (double*)(ws);
    unsigned char*  mask   = (unsigned char*)(ws + 512);
    unsigned short* value  = (unsigned short*)(ws + 512 + 131072);
    unsigned short* offawT = (unsigned short*)(ws + FIXED);

    // Chunk query range so 288*chunk*2 bytes of offawT always fits in ws.
    size_t avail = (ws_size > FIXED) ? (ws_size - FIXED) : 0;
    long long maxq = (long long)(avail / (288*2));
    int chunk = (int)((maxq/64)*64);
    if (chunk > NQ) chunk = NQ;
    if (chunk < 64) chunk = 64;   // round-2 pass proved ws_size >= 5.3 MB

    hipMemsetAsync(mask, 0, NQ, stream);
    inv_kernel<<<1, 64, 0, stream>>>(K, E, invm);
    mask_kernel<<<(NPIX+255)/256, 256, 0, stream>>>(depth, invm, vorig, mask);
    value_kernel<<<NVPIX/4, 128, 0, stream>>>(f0, f1, f2, Wv, bv, value);

    for (int q0 = 0; q0 < NQ; q0 += chunk){
        int len = (NQ - q0 < chunk) ? (NQ - q0) : chunk;
        offaw_kernel<<<len/64, 256, 0, stream>>>(scene + (size_t)q0*CDIM,
                                                 Woff, boff, Wattw, battw,
                                                 offawT, len);
        attn_kernel<<<len/16, 256, 0, stream>>>(scene, refpix, offawT, value,
                                                Wout, bout, lng, lnb, mask,
                                                (float*)d_out, q0, len);
    }
}

// Round 6
// 1631.623 us; speedup vs baseline: 3.0595x; 3.0595x over previous
//
#include <hip/hip_runtime.h>
#include <hip/hip_bf16.h>
#include <stdint.h>

#define XS 128
#define YS 128
#define ZS 8
#define NQ (XS*YS*ZS)        // 131072 queries
#define CDIM 128
#define NH 8
#define HD 16
#define DH 192
#define DW 640
#define NPIX (DH*DW)
#define NVPIX 10080          // 7680 + 1920 + 480

__device__ __forceinline__ float b2f(unsigned short u){
    union { unsigned int i; float f; } v; v.i = ((unsigned int)u) << 16; return v.f;
}
__device__ __forceinline__ unsigned short f2b(float f){
    __hip_bfloat16 h = __float2bfloat16(f);
    return *reinterpret_cast<unsigned short*>(&h);
}

// ---------------- inverse of K (3x3) and E (4x4), fp64, one thread ----------------
__global__ void inv_kernel(const float* __restrict__ K,
                           const float* __restrict__ E,
                           double* __restrict__ inv_out){
    if (threadIdx.x != 0 || blockIdx.x != 0) return;
    double k[3][3], e[4][4];
    for (int i=0;i<9;i++)  k[i/3][i%3] = (double)K[i];
    for (int i=0;i<16;i++) e[i/4][i%4] = (double)E[i];
    double det = k[0][0]*(k[1][1]*k[2][2]-k[1][2]*k[2][1])
               - k[0][1]*(k[1][0]*k[2][2]-k[1][2]*k[2][0])
               + k[0][2]*(k[1][0]*k[2][1]-k[1][1]*k[2][0]);
    double id = 1.0/det;
    double inv[3][3];
    inv[0][0]=(k[1][1]*k[2][2]-k[1][2]*k[2][1])*id;
    inv[0][1]=(k[0][2]*k[2][1]-k[0][1]*k[2][2])*id;
    inv[0][2]=(k[0][1]*k[1][2]-k[0][2]*k[1][1])*id;
    inv[1][0]=(k[1][2]*k[2][0]-k[1][0]*k[2][2])*id;
    inv[1][1]=(k[0][0]*k[2][2]-k[0][2]*k[2][0])*id;
    inv[1][2]=(k[0][2]*k[1][0]-k[0][0]*k[1][2])*id;
    inv[2][0]=(k[1][0]*k[2][1]-k[1][1]*k[2][0])*id;
    inv[2][1]=(k[0][1]*k[2][0]-k[0][0]*k[2][1])*id;
    inv[2][2]=(k[0][0]*k[1][1]-k[0][1]*k[1][0])*id;
    for (int i=0;i<9;i++) inv_out[i] = inv[i/3][i%3];
    double a[4][8];
    for (int i=0;i<4;i++){ for(int j=0;j<4;j++){ a[i][j]=e[i][j]; a[i][4+j]=(i==j)?1.0:0.0; } }
    for (int c=0;c<4;c++){
        int piv=c; double best=fabs(a[c][c]);
        for (int r=c+1;r<4;r++){ double v=fabs(a[r][c]); if (v>best){best=v;piv=r;} }
        if (piv!=c){ for (int j=0;j<8;j++){ double tmp=a[c][j]; a[c][j]=a[piv][j]; a[piv][j]=tmp; } }
        double pv = 1.0/a[c][c];
        for (int j=0;j<8;j++) a[c][j]*=pv;
        for (int r=0;r<4;r++){
            if (r==c) continue;
            double f=a[r][c];
            for(int j=0;j<8;j++) a[r][j]-=f*a[c][j];
        }
    }
    for (int i=0;i<16;i++) inv_out[9+i] = a[i/4][4 + (i%4)];
}

// ---------------- pix2vox + voxel mask ----------------
__global__ void mask_kernel(const float* __restrict__ depth,
                            const double* __restrict__ invm,
                            const float* __restrict__ vorigin,
                            unsigned char* __restrict__ mask){
    int tid = blockIdx.x*blockDim.x + threadIdx.x;
    if (tid >= NPIX) return;
    int gx = tid % DW, gy = tid / DW;
    double d  = (double)depth[tid];
    double X0 = (double)gx * d, X1 = (double)gy * d, X2 = d;
    double c0 = invm[0]*X0 + invm[1]*X1 + invm[2]*X2;
    double c1 = invm[3]*X0 + invm[4]*X1 + invm[5]*X2;
    double c2 = invm[6]*X0 + invm[7]*X1 + invm[8]*X2;
    const double* iE = invm + 9;
    double w0 = iE[0]*c0 + iE[1]*c1 + iE[2]*c2  + iE[3];
    double w1 = iE[4]*c0 + iE[5]*c1 + iE[6]*c2  + iE[7];
    double w2 = iE[8]*c0 + iE[9]*c1 + iE[10]*c2 + iE[11];
    double v0 = (w0-(double)vorigin[0])/0.4 - 0.5;
    double v1 = (w1-(double)vorigin[1])/0.4 - 0.5;
    double v2 = ((w2-(double)vorigin[2])/0.4 - 0.5) / 2.0;
    int xi = (int)v0, yi = (int)v1, zi = (int)v2;
    if (xi>=0 && xi<XS && yi>=0 && yi<YS && zi>=0 && zi<ZS)
        mask[(xi*YS + yi)*ZS + zi] = 1;
}

// ---------------- value = flat @ Wv.T + bv -> bf16, 4 pixels/block ----------------
__global__ __launch_bounds__(128)
void value_kernel(const float* __restrict__ f0,
                  const float* __restrict__ f1,
                  const float* __restrict__ f2,
                  const float* __restrict__ Wv,
                  const float* __restrict__ bv,
                  unsigned short* __restrict__ value){
    int p0 = blockIdx.x*4, t = threadIdx.x;
    __shared__ float fl[CDIM][4];
    const float* src; int hw, lp;
    if (p0 < 7680)      { src=f0; hw=7680; lp=p0; }
    else if (p0 < 9600) { src=f1; hw=1920; lp=p0-7680; }
    else                { src=f2; hw=480;  lp=p0-9600; }
    float4 v = *(const float4*)(src + t*hw + lp);
    fl[t][0]=v.x; fl[t][1]=v.y; fl[t][2]=v.z; fl[t][3]=v.w;
    __syncthreads();
    float bb = bv[t];
    float acc[4] = {bb,bb,bb,bb};
    const float4* wrow = (const float4*)(Wv + t*CDIM);
    #pragma unroll 8
    for (int kc=0; kc<32; ++kc){
        float4 w = wrow[kc];
        #pragma unroll
        for (int u=0;u<4;u++){
            float wu = (u==0)?w.x:(u==1)?w.y:(u==2)?w.z:w.w;
            float4 fv = *(const float4*)fl[kc*4+u];
            acc[0] += fv.x*wu; acc[1] += fv.y*wu; acc[2] += fv.z*wu; acc[3] += fv.w*wu;
        }
    }
    #pragma unroll
    for (int i=0;i<4;i++)
        value[(size_t)(p0+i)*CDIM + t] = f2b(acc[i]);
}

// ---------------- offsets+logits GEMM: [288 x len] bf16, transposed output ----------------
__global__ __launch_bounds__(256)
void offaw_kernel(const float* __restrict__ q_in,      // chunk base
                  const float* __restrict__ Woff,
                  const float* __restrict__ boff,
                  const float* __restrict__ Wattw,
                  const float* __restrict__ battw,
                  unsigned short* __restrict__ offawT, // [288][len]
                  int len){
    const int n0 = blockIdx.x * 64;
    const int t = threadIdx.x;
    __shared__ float Qs[64][129];
    for (int idx = t; idx < 64*CDIM; idx += 256){
        int n = idx >> 7, c = idx & 127;
        Qs[n][c] = q_in[(size_t)(n0+n)*CDIM + c];
    }
    __syncthreads();
    const int w = t >> 6, lane = t & 63;
    for (int g = 0; g < 6; ++g){
        const int j0 = w*72 + g*12;
        const float* Wb; const float* bb;
        if (j0 < 192){ Wb = Woff  + (size_t)j0*CDIM;       bb = boff  + j0; }
        else         { Wb = Wattw + (size_t)(j0-192)*CDIM; bb = battw + (j0-192); }
        float acc[12];
        #pragma unroll
        for (int r=0;r<12;r++) acc[r] = bb[r];
        #pragma unroll 2
        for (int kc = 0; kc < 32; ++kc){
            float q0 = Qs[lane][kc*4+0];
            float q1 = Qs[lane][kc*4+1];
            float q2 = Qs[lane][kc*4+2];
            float q3 = Qs[lane][kc*4+3];
            #pragma unroll
            for (int r=0;r<12;r++){
                float4 w4 = *(const float4*)(Wb + r*CDIM + kc*4);
                acc[r] += q0*w4.x + q1*w4.y + q2*w4.z + q3*w4.w;
            }
        }
        #pragma unroll
        for (int r=0;r<12;r++)
            offawT[(size_t)(j0+r)*len + n0 + lane] = f2b(acc[r]);
    }
}

// ---------------- sampling + Wout + LN + mask + transposed store ----------------
// Block: 256 threads, 8 queries (4 per thread). Sampling: c=t&15, h=(t>>4)&7, qg=t>>7.
__global__ __launch_bounds__(256, 2)
void attn_kernel(const float* __restrict__ q_in,
                 const float* __restrict__ refpix,
                 const unsigned short* __restrict__ offawT, // [288][len], chunk-local
                 const unsigned short* __restrict__ value,
                 const float* __restrict__ Wout,
                 const float* __restrict__ bout,
                 const float* __restrict__ lng,
                 const float* __restrict__ lnb,
                 const unsigned char* __restrict__ mask,
                 float* __restrict__ dout,
                 int q0g, int len){
    const int n0l = blockIdx.x * 8;         // chunk-local
    const int n0g = q0g + n0l;              // global query index
    const int t = threadIdx.x;
    __shared__ float offaw_s[288][9];
    __shared__ float q_s[8][CDIM];
    __shared__ float out_s[8][CDIM];
    __shared__ float rp_s[16];
    __shared__ float wred[2][4][4];
    __shared__ unsigned char mask_s[8];

    for (int idx = t; idx < 288*8; idx += 256){
        int j = idx >> 3, qi = idx & 7;
        offaw_s[j][qi] = b2f(offawT[(size_t)j*len + n0l + qi]);
    }
    for (int idx = t; idx < 8*CDIM; idx += 256)
        ((float*)q_s)[idx] = q_in[(size_t)n0g*CDIM + idx];
    if (t < 16) rp_s[t] = refpix[n0g*2 + t];
    if (t < 8)  mask_s[t] = mask[n0g + t];
    __syncthreads();

    // softmax over 12 per (query, head): 64 threads
    if (t < 64){
        int qi = t >> 3, h = t & 7;
        float m = -1e30f;
        #pragma unroll
        for (int i=0;i<12;i++) m = fmaxf(m, offaw_s[192+h*12+i][qi]);
        float e[12]; float s = 0.f;
        #pragma unroll
        for (int i=0;i<12;i++){ e[i] = __expf(offaw_s[192+h*12+i][qi]-m); s += e[i]; }
        float is = 1.f/s;
        #pragma unroll
        for (int i=0;i<12;i++) offaw_s[192+h*12+i][qi] = e[i]*is;
    }
    __syncthreads();

    // bilinear sampling, 4 queries per thread
    const int c = t & 15, h = (t>>4)&7, qg = t>>7;
    const unsigned short* vbase = value + h*HD + c;
    float accv[4] = {0.f,0.f,0.f,0.f};
    const int Wl[3]={160,80,40}, Hl[3]={48,24,12}, stl[3]={0,7680,9600};
    #pragma unroll
    for (int l=0;l<3;l++){
        const float fw = (float)Wl[l], fh = (float)Hl[l];
        #pragma unroll 2
        for (int p=0;p<4;p++){
            const int orow = ((h*3+l)*4+p)*2;
            const int arow = 192 + h*12 + l*4 + p;
            #pragma unroll
            for (int qi4=0;qi4<4;qi4++){
                int qi = qg*4+qi4;
                float x = rp_s[qi*2+0]*fw - 0.5f + offaw_s[orow][qi];
                float y = rp_s[qi*2+1]*fh - 0.5f + offaw_s[orow+1][qi];
                float x0f = floorf(x), y0f = floorf(y);
                float lx = x-x0f, ly = y-y0f;
                int x0 = (int)x0f, y0 = (int)y0f;
                bool x0ok = (x0 >= 0) && (x0 < Wl[l]);
                bool x1ok = (x0+1 >= 0) && (x0+1 < Wl[l]);
                bool y0ok = (y0 >= 0) && (y0 < Hl[l]);
                bool y1ok = (y0+1 >= 0) && (y0+1 < Hl[l]);
                int base = stl[l] + y0*Wl[l] + x0;
                float v00 = (x0ok&&y0ok) ? b2f(vbase[(size_t)base*CDIM])            : 0.f;
                float v01 = (x1ok&&y0ok) ? b2f(vbase[(size_t)(base+1)*CDIM])        : 0.f;
                float v10 = (x0ok&&y1ok) ? b2f(vbase[(size_t)(base+Wl[l])*CDIM])    : 0.f;
                float v11 = (x1ok&&y1ok) ? b2f(vbase[(size_t)(base+Wl[l]+1)*CDIM])  : 0.f;
                float s = (v00*(1.f-lx)+v01*lx)*(1.f-ly) + (v10*(1.f-lx)+v11*lx)*ly;
                accv[qi4] = fmaf(offaw_s[arow][qi], s, accv[qi4]);
            }
        }
    }
    #pragma unroll
    for (int qi4=0;qi4<4;qi4++) out_s[qg*4+qi4][h*HD+c] = accv[qi4];
    __syncthreads();

    // attn = out @ Wout.T + bout, 4 queries per thread (r = t&127)
    const int r = t & 127;
    float acc[4];
    { float bb = bout[r];
      #pragma unroll
      for (int qi4=0;qi4<4;qi4++) acc[qi4]=bb; }
    const float4* w4p = (const float4*)(Wout + (size_t)r*CDIM);
    #pragma unroll 8
    for (int kc=0;kc<32;kc++){
        float4 w = w4p[kc];
        #pragma unroll
        for (int qi4=0;qi4<4;qi4++){
            const float* os = out_s[qg*4+qi4];
            acc[qi4] += os[kc*4+0]*w.x + os[kc*4+1]*w.y
                      + os[kc*4+2]*w.z + os[kc*4+3]*w.w;
        }
    }

    // residual + LayerNorm + mask + transposed store
    const int wv = t >> 6;
    float hv[4], sred[4];
    #pragma unroll
    for (int qi4=0;qi4<4;qi4++){ hv[qi4] = q_s[qg*4+qi4][r] + acc[qi4]; sred[qi4]=hv[qi4]; }
    #pragma unroll
    for (int off=32; off>0; off>>=1)
        #pragma unroll
        for (int qi4=0;qi4<4;qi4++) sred[qi4] += __shfl_xor(sred[qi4], off, 64);
    if ((t&63)==0){
        #pragma unroll
        for (int qi4=0;qi4<4;qi4++) wred[0][wv][qi4]=sred[qi4];
    }
    __syncthreads();
    float mu[4], dv[4];
    #pragma unroll
    for (int qi4=0;qi4<4;qi4++){
        mu[qi4] = (wred[0][qg*2][qi4]+wred[0][qg*2+1][qi4]) * (1.f/128.f);
        dv[qi4] = hv[qi4]-mu[qi4];
        sred[qi4] = dv[qi4]*dv[qi4];
    }
    #pragma unroll
    for (int off=32; off>0; off>>=1)
        #pragma unroll
        for (int qi4=0;qi4<4;qi4++) sred[qi4] += __shfl_xor(sred[qi4], off, 64);
    if ((t&63)==0){
        #pragma unroll
        for (int qi4=0;qi4<4;qi4++) wred[1][wv][qi4]=sred[qi4];
    }
    __syncthreads();

    float res[4];
    const float g = lng[r], b = lnb[r];
    #pragma unroll
    for (int qi4=0;qi4<4;qi4++){
        float var = (wred[1][qg*2][qi4]+wred[1][qg*2+1][qi4]) * (1.f/128.f);
        float nv  = dv[qi4] * __frsqrt_rn(var + 1e-5f) * g + b;
        res[qi4] = mask_s[qg*4+qi4] ? nv : q_s[qg*4+qi4][r];
    }
    float4 o; o.x=res[0]; o.y=res[1]; o.z=res[2]; o.w=res[3];
    *(float4*)(dout + (size_t)r*NQ + n0g + qg*4) = o;
}

extern "C" void kernel_launch(void* const* d_in, const int* in_sizes, int n_in,
                              void* d_out, int out_size, void* d_ws, size_t ws_size,
                              hipStream_t stream){
    const float* scene  = (const float*)d_in[0];
    const float* f0     = (const float*)d_in[1];
    const float* f1     = (const float*)d_in[2];
    const float* f2     = (const float*)d_in[3];
    const float* depth  = (const float*)d_in[4];
    const float* K      = (const float*)d_in[5];
    const float* E      = (const float*)d_in[6];
    const float* vorig  = (const float*)d_in[7];
    const float* refpix = (const float*)d_in[8];
    const float* Wv     = (const float*)d_in[9];
    const float* bv     = (const float*)d_in[10];
    const float* Woff   = (const float*)d_in[11];
    const float* boff   = (const float*)d_in[12];
    const float* Wattw  = (const float*)d_in[13];
    const float* battw  = (const float*)d_in[14];
    const float* Wout   = (const float*)d_in[15];
    const float* bout   = (const float*)d_in[16];
    const float* lng    = (const float*)d_in[17];
    const float* lnb    = (const float*)d_in[18];

    char* ws = (char*)d_ws;
    const size_t FIXED = 512 + 131072 + 2580480;           // invm + mask + value
    double*         invm   = (double*)(ws);
    unsigned char*  mask   = (unsigned char*)(ws + 512);
    unsigned short* value  = (unsigned short*)(ws + 512 + 131072);
    unsigned short* offawT = (unsigned short*)(ws + FIXED);

    // Chunk query range so 288*chunk*2 bytes of offawT always fits in ws.
    size_t avail = (ws_size > FIXED) ? (ws_size - FIXED) : 0;
    long long maxq = (long long)(avail / (288*2));
    int chunk = (int)((maxq/64)*64);
    if (chunk > NQ) chunk = NQ;
    if (chunk < 64) chunk = 64;

    hipMemsetAsync(mask, 0, NQ, stream);
    inv_kernel<<<1, 64, 0, stream>>>(K, E, invm);
    mask_kernel<<<(NPIX+255)/256, 256, 0, stream>>>(depth, invm, vorig, mask);
    value_kernel<<<NVPIX/4, 128, 0, stream>>>(f0, f1, f2, Wv, bv, value);

    for (int q0 = 0; q0 < NQ; q0 += chunk){
        int len = (NQ - q0 < chunk) ? (NQ - q0) : chunk;
        offaw_kernel<<<len/64, 256, 0, stream>>>(scene + (size_t)q0*CDIM,
                                                 Woff, boff, Wattw, battw,
                                                 offawT, len);
        attn_kernel<<<len/8, 256, 0, stream>>>(scene, refpix, offawT, value,
                                               Wout, bout, lng, lnb, mask,
                                               (float*)d_out, q0, len);
    }
}